// Round 7
// baseline (296.130 us; speedup 1.0000x reference)
//
#include <hip/hip_runtime.h>
#include <hip/hip_bf16.h>

#define B_     32
#define C_     256
#define T_     4096
#define NH_    8
#define DH_    64
#define JT_    64                 // j per tile
#define NT_    (T_ / JT_)         // 64 tiles
#define XP_    65                 // xs pitch: (65c+j)%32 spreads -> 2-way (free)

// ---------------------------------------------------------------------------
// K1: fold q-projection into Wkv_k.
//   qW[b,c,n] = scale * sum_d q[b,n,d] * Wkv[n*64+d, c]
//   qb[b,n]   = scale * sum_d q[b,n,d] * bkv[n*64+d]
// grid (NH_, B_) = 256 blocks, block 256.  (unchanged, measured fine)
// ---------------------------------------------------------------------------
__global__ __launch_bounds__(256) void k_prep(
    const float* __restrict__ query, const float* __restrict__ Wkv,
    const float* __restrict__ bkv, const float* __restrict__ Wq,
    const float* __restrict__ bq, float* __restrict__ qWt,
    float* __restrict__ qb) {
  const int n = blockIdx.x;
  const int b = blockIdx.y;
  const int t = threadIdx.x;
  __shared__ float qrow_s[C_];
  __shared__ float psum[4 * 64];
  __shared__ float qsh[64];
  __shared__ float pb_s[64];

  qrow_s[t] = query[(size_t)b * C_ + t];
  __syncthreads();

  {
    const int d = t & 63, ch = t >> 6;
    const float* wrow = Wq + (size_t)(n * DH_ + d) * C_ + ch * 64;
    const float* qr = qrow_s + ch * 64;
    float s = 0.f;
    #pragma unroll
    for (int c = 0; c < 64; c += 4) {
      float4 w = *(const float4*)(wrow + c);
      s += w.x * qr[c] + w.y * qr[c + 1] + w.z * qr[c + 2] + w.w * qr[c + 3];
    }
    psum[ch * 64 + d] = s;
  }
  __syncthreads();
  if (t < 64)
    qsh[t] = bq[n * DH_ + t] + psum[t] + psum[64 + t] + psum[128 + t] + psum[192 + t];
  __syncthreads();

  const float scale = 0.125f;
  {
    const float* wk = Wkv + (size_t)(n * DH_) * C_ + t;
    float acc = 0.f;
    #pragma unroll 8
    for (int dd = 0; dd < DH_; ++dd) acc += qsh[dd] * wk[(size_t)dd * C_];
    qWt[((size_t)b * C_ + t) * NH_ + n] = acc * scale;
  }
  if (t < 64) pb_s[t] = qsh[t] * bkv[n * DH_ + t];
  __syncthreads();
  if (t == 0) {
    float s = 0.f;
    #pragma unroll 8
    for (int dd = 0; dd < 64; ++dd) s += pb_s[dd];
    qb[b * NH_ + n] = s * scale;
  }
}

// ---------------------------------------------------------------------------
// K2 (fused, single x pass): per (tile, b) block —
//   stage x[256c x 64j] in LDS once;
//   A: logits l[j,n] = qb + sum_c qW[b,c,n] x[c,j]  (thread = (j, c-chunk))
//   local softmax: m[n] = max_j l, ew[j,n] = exp(l - m), s[n] = sum ew
//   B: part[b,tile,n,c] = sum_j ew[j,n] * x[c,j]    (thread = c)
//   stats[b,tile,n] = (m, s)
// grid (NT_, B_) = 2048 blocks, 256 threads, LDS ~76 KB -> 2 blocks/CU.
// ---------------------------------------------------------------------------
__global__ __launch_bounds__(256) void k_fused(
    const float* __restrict__ x, const float* __restrict__ qWt,
    const float* __restrict__ qbv, float* __restrict__ part,
    float* __restrict__ stats) {
  const int tile = blockIdx.x;
  const int b    = blockIdx.y;
  const int t    = threadIdx.x;
  const int j0   = tile * JT_;

  __shared__ float xs[C_ * XP_];      // 66560 B
  __shared__ float lsc[4 * 576];      // 9216 B; chunk ch at ch*576, slot j*9+n
  // after combine: lsc[0..575] holds lfull[j*9+n]; lsc[576..] reused as ew[j*8+n]
  float* const ew = lsc + 576;        // 16B-aligned (2304 B offset)

  const float* xb = x + (size_t)b * C_ * T_ + j0;

  // ---- stage x tile (coalesced: 16 lanes = 256B row segment) ----
  {
    const int cg = t >> 4;            // 0..15
    const int jc = (t & 15) * 4;      // 0..60
    #pragma unroll 4
    for (int p = 0; p < 16; ++p) {
      const int c = cg + p * 16;
      float4 v = *(const float4*)(xb + (size_t)c * T_ + jc);
      float* d = &xs[c * XP_ + jc];
      d[0] = v.x; d[1] = v.y; d[2] = v.z; d[3] = v.w;
    }
  }
  __syncthreads();

  // ---- phase A: logits partials; wave-uniform qW -> scalar loads ----
  {
    const int j  = t & 63;
    const int ch = t >> 6;            // wave-uniform
    const float* qw = qWt + ((size_t)b * C_ + ch * 64) * NH_;
    float al[NH_];
    #pragma unroll
    for (int n = 0; n < NH_; ++n) al[n] = 0.f;
    #pragma unroll 4
    for (int cc = 0; cc < 64; ++cc) {
      const float xv = xs[(ch * 64 + cc) * XP_ + j];   // 2-way, free
      const float* qwc = qw + cc * NH_;                // uniform -> SGPR
      #pragma unroll
      for (int n = 0; n < NH_; ++n) al[n] += qwc[n] * xv;
    }
    float* dst = &lsc[ch * 576 + j * 9];
    #pragma unroll
    for (int n = 0; n < NH_; ++n) dst[n] = al[n];
  }
  __syncthreads();

  // ---- combine chunks + bias (in place into chunk 0) ----
  {
    const float* qb = qbv + b * NH_;
    #pragma unroll
    for (int r = 0; r < 2; ++r) {
      const int s = r * 256 + t;      // 0..511
      const int j = s >> 3, n = s & 7;
      const int idx = j * 9 + n;
      const float l = lsc[idx] + lsc[576 + idx] + lsc[1152 + idx] +
                      lsc[1728 + idx] + qb[n];
      lsc[idx] = l;                   // own slot only: no cross-thread hazard
    }
  }
  __syncthreads();

  // ---- tile-local softmax stats (threads 0..7, one head each) ----
  if (t < NH_) {
    float m = -3.4e38f;
    for (int j = 0; j < JT_; ++j) m = fmaxf(m, lsc[j * 9 + t]);
    float s = 0.f;
    for (int j = 0; j < JT_; ++j) {
      const float e = __expf(lsc[j * 9 + t] - m);
      ew[j * 8 + t] = e;              // 8 lanes, distinct banks
      s += e;
    }
    float* st = stats + (((size_t)b * NT_ + tile) * NH_ + t) * 2;
    st[0] = m; st[1] = s;
  }
  __syncthreads();

  // ---- phase B: exp-weighted accumulation; thread owns c = t ----
  {
    float acc[NH_];
    #pragma unroll
    for (int n = 0; n < NH_; ++n) acc[n] = 0.f;
    const float* xr = &xs[t * XP_];
    #pragma unroll 4
    for (int j = 0; j < JT_; ++j) {
      const float xv = xr[j];                          // (t+j)%32: 2-way, free
      const float4 e0 = *(const float4*)(ew + j * 8);  // broadcast b128
      const float4 e1 = *(const float4*)(ew + j * 8 + 4);
      acc[0] += e0.x * xv; acc[1] += e0.y * xv;
      acc[2] += e0.z * xv; acc[3] += e0.w * xv;
      acc[4] += e1.x * xv; acc[5] += e1.y * xv;
      acc[6] += e1.z * xv; acc[7] += e1.w * xv;
    }
    float* pb = part + (((size_t)b * NT_ + tile) * NH_) * C_;
    #pragma unroll
    for (int n = 0; n < NH_; ++n) pb[n * C_ + t] = acc[n];
  }
}

// ---------------------------------------------------------------------------
// K3 (merge): two-level softmax combine across tiles.
//   M[n] = max_t m_t ; Z[n] = sum_t s_t e^{m_t-M}
//   xattn[b,n,c] = sum_t e^{m_t-M} part[b,t,n,c] / Z
// grid (NH_, B_) = 256 blocks, block 256 (thread = c).
// ---------------------------------------------------------------------------
__global__ __launch_bounds__(256) void k_merge(
    const float* __restrict__ part, const float* __restrict__ stats,
    float* __restrict__ xattnG) {
  const int n = blockIdx.x;
  const int b = blockIdx.y;
  const int t = threadIdx.x;
  __shared__ float mm[NT_], sv[NT_], wsc[NT_];

  if (t < NT_) {
    const float* st = stats + (((size_t)b * NT_ + t) * NH_ + n) * 2;
    mm[t] = st[0]; sv[t] = st[1];
  }
  __syncthreads();

  float M = -3.4e38f;
  #pragma unroll 8
  for (int i = 0; i < NT_; ++i) M = fmaxf(M, mm[i]);   // broadcast reads
  if (t < NT_) wsc[t] = __expf(mm[t] - M);
  __syncthreads();
  float Z = 0.f;
  #pragma unroll 8
  for (int i = 0; i < NT_; ++i) Z += sv[i] * wsc[i];
  const float invZ = 1.0f / Z;

  const float* pb = part + (((size_t)b * NT_) * NH_ + n) * C_ + t;
  float acc = 0.f;
  #pragma unroll 4
  for (int i = 0; i < NT_; ++i)
    acc += wsc[i] * pb[(size_t)i * NH_ * C_];          // coalesced over c
  xattnG[((size_t)b * NH_ + n) * C_ + t] = acc * invZ;
}

// ---------------------------------------------------------------------------
// K4 (tail): per batch b —
//   outv[o]  = bkv[512+o] + Wkv[512+o,:]·xattn[o>>6,:]
//   out[b,m] = relu(bfc[m] + Wfc[m,:]·outv)
// grid B_, block 512.
// ---------------------------------------------------------------------------
__global__ __launch_bounds__(512) void k_tail(
    const float* __restrict__ xattnG, const float* __restrict__ Wkv,
    const float* __restrict__ bkv, const float* __restrict__ Wfc,
    const float* __restrict__ bfc, float* __restrict__ out) {
  __shared__ float xa_s[NH_ * C_];  // 8 KB
  __shared__ float ov[512];
  const int b = blockIdx.x;
  const int t = threadIdx.x;

  #pragma unroll
  for (int r = 0; r < 4; ++r)
    xa_s[r * 512 + t] = xattnG[(size_t)b * (NH_ * C_) + r * 512 + t];
  __syncthreads();

  {
    const int o = t;                         // 0..511
    const float* wrow = Wkv + (size_t)(512 + o) * C_;
    const float* xa = &xa_s[(o >> 6) * C_];  // wave-uniform head -> broadcast
    float s = bkv[512 + o];
    #pragma unroll 8
    for (int c = 0; c < C_; c += 4) {
      float4 w = *(const float4*)(wrow + c);
      s += w.x * xa[c] + w.y * xa[c + 1] + w.z * xa[c + 2] + w.w * xa[c + 3];
    }
    ov[o] = s;
  }
  __syncthreads();

  if (t < 256) {
    const int m = t;
    const float* wrow = Wfc + (size_t)m * 512;
    float s = bfc[m];
    #pragma unroll 8
    for (int o = 0; o < 512; o += 4) {
      float4 w = *(const float4*)(wrow + o);
      s += w.x * ov[o] + w.y * ov[o + 1] + w.z * ov[o + 2] + w.w * ov[o + 3];
    }
    out[(size_t)b * 256 + m] = fmaxf(s, 0.f);
  }
}

// ---------------------------------------------------------------------------
extern "C" void kernel_launch(void* const* d_in, const int* in_sizes, int n_in,
                              void* d_out, int out_size, void* d_ws, size_t ws_size,
                              hipStream_t stream) {
  const float* x     = (const float*)d_in[0];
  const float* query = (const float*)d_in[1];
  const float* Wkv   = (const float*)d_in[2];
  const float* bkv   = (const float*)d_in[3];
  const float* Wq    = (const float*)d_in[4];
  const float* bq    = (const float*)d_in[5];
  const float* Wfc   = (const float*)d_in[6];
  const float* bfc   = (const float*)d_in[7];
  float* out = (float*)d_out;
  float* ws  = (float*)d_ws;

  // workspace (floats)
  float* qWt    = ws;                  // 32*256*8         = 65536
  float* qb     = ws + 65536;          // 256 (pad 512)
  float* part   = ws + 66048;          // 32*64*8*256      = 4194304
  float* stats  = ws + 4260352;        // 32*64*8*2        = 32768
  float* xattnG = ws + 4293120;        // 32*8*256         = 65536
  // total ~4.36M floats = 17.4 MB

  k_prep <<<dim3(NH_, B_), 256, 0, stream>>>(query, Wkv, bkv, Wq, bq, qWt, qb);
  k_fused<<<dim3(NT_, B_), 256, 0, stream>>>(x, qWt, qb, part, stats);
  k_merge<<<dim3(NH_, B_), 256, 0, stream>>>(part, stats, xattnG);
  k_tail <<<B_,            512, 0, stream>>>(xattnG, Wkv, bkv, Wfc, bfc, out);
}